// Round 10
// baseline (153.508 us; speedup 1.0000x reference)
//
#include <hip/hip_runtime.h>
#include <hip/hip_bf16.h>

// ---------------------------------------------------------------------------
// NeighborhoodAttentionBlock: B=2, H=W=64, C=256, nh=4, hd=64, k=7
// R10: BM=16 tiling for fused_qkv (6 blk/CU) and fused_tail (2 blk/CU)
//      to hide staging-barrier latency. attn = R5-verified. 5 dispatches.
// ---------------------------------------------------------------------------

#define ROWS 8192
typedef unsigned int uint32;
typedef unsigned short ushort16;
typedef __attribute__((ext_vector_type(8))) short short8;
typedef __attribute__((ext_vector_type(4))) float floatx4;

__device__ __forceinline__ float bf2f(__hip_bfloat16 b) { return __bfloat162float(b); }
__device__ __forceinline__ float us2f(ushort16 u) {
    return __uint_as_float(((uint32)u) << 16);
}
__device__ __forceinline__ ushort16 f2us(float f) {
    __hip_bfloat16 h = __float2bfloat16(f);
    return *(ushort16*)&h;
}
__device__ __forceinline__ float ldflag(const void* p, size_t i, int f32) {
    return f32 ? ((const float*)p)[i] : bf2f(((const __hip_bfloat16*)p)[i]);
}

__device__ __forceinline__ void gl_lds16(const void* gptr, void* lptr) {
    __builtin_amdgcn_global_load_lds(
        (const __attribute__((address_space(1))) uint32*)gptr,
        (__attribute__((address_space(3))) uint32*)lptr, 16, 0, 0);
}

// Fast exact-erf gelu: Abramowitz-Stegun 7.1.26 (max err 1.5e-7) + __expf.
__device__ __forceinline__ float gelu_f(float gate) {
    const float z = gate * 0.70710678118654752f;
    const float az = fabsf(z);
    const float t1 = 1.0f / fmaf(0.3275911f, az, 1.0f);
    const float poly = ((((1.061405429f * t1 - 1.453152027f) * t1 + 1.421413741f) * t1
                         - 0.284496736f) * t1 + 0.254829592f) * t1;
    float erfv = 1.0f - poly * __expf(-az * az);
    erfv = (z < 0.0f) ? -erfv : erfv;
    return 0.5f * gate * (1.0f + erfv);
}

// ---------------------------------------------------------------------------
// Dtype detector (verified).
// ---------------------------------------------------------------------------
__global__ __launch_bounds__(64) void detect_kernel(const ushort16* __restrict__ xu,
                                                    int* __restrict__ flag) {
    const int lane = threadIdx.x;
    const float v = us2f(xu[lane * 62]);
    const float a = fabsf(v);
    const bool sane = (a < 1e4f) && (a > 1e-8f);
    const unsigned long long m = __ballot(sane);
    if (lane == 0) flag[0] = (__popcll(m) < 32) ? 1 : 0;
}

// ---------------------------------------------------------------------------
// Weight convert + transpose (verified) + bias block + rope LUT block.
// ---------------------------------------------------------------------------
struct WSrc {
    const void *wqkv, *wproj, *ff1w, *ff2w, *bproj, *ff1b, *ff2b;
};
__global__ __launch_bounds__(256) void cvt_kernel(WSrc s, ushort16* __restrict__ wT,
                                                  float* __restrict__ bF,
                                                  float2* __restrict__ lut,
                                                  const int* __restrict__ flag) {
    const int f32 = flag[0];
    const int bid = blockIdx.x, tid = threadIdx.x;
    if (bid == 112) {
        #pragma unroll
        for (int it = 0; it < 4; ++it) {
            const int j = it * 256 + tid;
            float v;
            if (j < 256)      v = ldflag(s.bproj, j, f32);
            else if (j < 768) v = ldflag(s.ff1b, j - 256, f32);
            else              v = ldflag(s.ff2b, j - 768, f32);
            bF[j] = v;
        }
        return;
    }
    if (bid == 113) {
        #pragma unroll
        for (int it = 0; it < 16; ++it) {
            const int idx = it * 256 + tid;       // 0..4095
            const int pos = idx >> 6, j = idx & 63;
            const float inv = expf(-(float)j * (9.210340371976184f / 64.0f));
            const float th = (float)pos * inv;
            lut[idx] = make_float2(cosf(th), sinf(th));
        }
        return;
    }
    const void* src; int N, kt, nt, base;
    if (bid < 48)      { src = s.wqkv;  N = 768; kt = bid / 12;      nt = bid % 12;      base = 0; }
    else if (bid < 64) { const int l = bid - 48; src = s.wproj; N = 256; kt = l / 4; nt = l % 4; base = 196608; }
    else if (bid < 96) { const int l = bid - 64; src = s.ff1w;  N = 512; kt = l / 8; nt = l % 8; base = 262144; }
    else               { const int l = bid - 96; src = s.ff2w;  N = 256; kt = l / 4; nt = l % 4; base = 393216; }

    __shared__ ushort16 T[64][65];
    const int r0 = tid >> 6, c = tid & 63;
    #pragma unroll
    for (int j = 0; j < 16; ++j) {
        const int r = j * 4 + r0;
        T[r][c] = f2us(ldflag(src, (size_t)(kt * 64 + r) * N + nt * 64 + c, f32));
    }
    __syncthreads();
    const int n = tid >> 2, kg = tid & 3;
    #pragma unroll
    for (int j = 0; j < 16; ++j) {
        const int k = kg * 16 + j;
        wT[base + (size_t)(nt * 64 + n) * 256 + kt * 64 + k] = T[k][n];
    }
}

// ---------------------------------------------------------------------------
// FUSED rmsnorm1 + rope2d + qkv GEMM. BM=16, grid (3, 512), ~25 KB LDS
// -> 6 blocks/CU. Phase 0: 16 threads/row, 16 elems each.
// ---------------------------------------------------------------------------
__global__ __launch_bounds__(256) void fused_qkv(const void* __restrict__ x,
                                                 const void* __restrict__ n1w,
                                                 const ushort16* __restrict__ wqkvT,
                                                 const float2* __restrict__ lut,
                                                 ushort16* __restrict__ qkv,
                                                 const int* __restrict__ flag) {
    __shared__ ushort16 Apad[16 * 264];
    __shared__ ushort16 Bs[256 * 32];

    const int f32 = flag[0];
    const int tid = threadIdx.x, lane = tid & 63, wid = tid >> 6;
    const int l15 = lane & 15, kq8 = (lane >> 4) * 8;
    const int n0 = blockIdx.x * 256, m0 = blockIdx.y * 16;
    const int nw = wid * 64;
    const int cr = lane >> 2, cc = (lane & 3) * 8;

    // ---- phase 0: norm + rope (LUT). row = tid>>4 (16 rows), s = tid&15. ----
    {
        const int row = tid >> 4, s = tid & 15;
        const int gm = m0 + row;
        float v[16];
        #pragma unroll
        for (int j = 0; j < 4; ++j) {
            const size_t off = (size_t)gm * 256 + s * 16 + j * 4;
            if (f32) {
                const float4 d = *(const float4*)((const float*)x + off);
                v[j * 4] = d.x; v[j * 4 + 1] = d.y; v[j * 4 + 2] = d.z; v[j * 4 + 3] = d.w;
            } else {
                const ushort4 d = *(const ushort4*)((const ushort16*)x + off);
                v[j * 4] = us2f(d.x); v[j * 4 + 1] = us2f(d.y);
                v[j * 4 + 2] = us2f(d.z); v[j * 4 + 3] = us2f(d.w);
            }
        }
        float sq = 0.0f;
        #pragma unroll
        for (int i = 0; i < 16; ++i) sq += v[i] * v[i];
        sq += __shfl_xor(sq, 1);
        sq += __shfl_xor(sq, 2);
        sq += __shfl_xor(sq, 4);
        sq += __shfl_xor(sq, 8);
        const float rr = rsqrtf(sq * (1.0f / 256.0f) + 1e-6f);

        const int py = (gm >> 6) & 63, px = gm & 63;
        #pragma unroll
        for (int j = 0; j < 4; ++j) {
            const int c0 = s * 16 + j * 4;
            float nv[4];
            #pragma unroll
            for (int u = 0; u < 4; ++u)
                nv[u] = v[j * 4 + u] * rr * ldflag(n1w, c0 + u, f32);
            const int pos = (c0 < 128) ? py : px;
            const int j0 = (c0 & 127) >> 1;
            #pragma unroll
            for (int p = 0; p < 2; ++p) {
                const float2 cs = lut[pos * 64 + j0 + p];
                const float a = nv[p * 2], b = nv[p * 2 + 1];
                nv[p * 2]     = a * cs.x - b * cs.y;
                nv[p * 2 + 1] = a * cs.y + b * cs.x;
            }
            ushort4 o;
            o.x = f2us(nv[0]); o.y = f2us(nv[1]); o.z = f2us(nv[2]); o.w = f2us(nv[3]);
            *(ushort4*)&Apad[row * 264 + c0] = o;
        }
    }
    __syncthreads();

    floatx4 acc[4] = {};
    for (int k0 = 0; k0 < 256; k0 += 32) {
        #pragma unroll
        for (int c = 0; c < 4; ++c) {
            const int ch = wid + c * 4;    // 0..15
            gl_lds16(wqkvT + (size_t)(n0 + ch * 16 + cr) * 256 + k0 + cc, Bs + ch * 512);
        }
        __syncthreads();
        short8 af, bf[4];
        af = *(const short8*)&Apad[l15 * 264 + k0 + kq8];
        #pragma unroll
        for (int nj = 0; nj < 4; ++nj)
            bf[nj] = *(const short8*)&Bs[(nw + nj * 16 + l15) * 32 + kq8];
        #pragma unroll
        for (int nj = 0; nj < 4; ++nj)
            acc[nj] = __builtin_amdgcn_mfma_f32_16x16x32_bf16(af, bf[nj], acc[nj], 0, 0, 0);
        __syncthreads();
    }

    const int crow = (lane >> 4) * 4;
    #pragma unroll
    for (int nj = 0; nj < 4; ++nj)
        #pragma unroll
        for (int r = 0; r < 4; ++r) {
            const int m = m0 + crow + r;
            const int n = n0 + nw + nj * 16 + l15;
            qkv[(size_t)m * 768 + n] = f2us(acc[nj][r]);
        }
}

// ---------------------------------------------------------------------------
// Neighborhood attention (R5-verified version, unchanged).
// ---------------------------------------------------------------------------
__global__ __launch_bounds__(256) void attn_kernel(const ushort16* __restrict__ qkv,
                                                   ushort16* __restrict__ ao) {
    __shared__ ushort16 smem[40208];
    ushort16* const KS = smem;
    ushort16* const VT = smem + 12544;
    ushort16* const PL = smem + 26880;

    const int tid = threadIdx.x, lane = tid & 63, wid = tid >> 6;
    const int l15 = lane & 15, kq8 = (lane >> 4) * 8;
    const int bid = blockIdx.x;
    const int h = bid & 3;
    const int t = (bid >> 2) & 63;
    const int b = bid >> 8;
    const int ty0 = (t >> 3) * 8, tx0 = (t & 7) * 8;
    const int hby = min(max(ty0 - 3, 0), 50);
    const int hbx = min(max(tx0 - 3, 0), 50);
    const int hcol = h * 64;

    const int qpl = wid * 16 + l15;
    const int qpy = ty0 + (qpl >> 3), qpx = tx0 + (qpl & 7);
    const size_t qoff = (size_t)(b * 4096 + qpy * 64 + qpx) * 768 + hcol + kq8;
    const short8 af0 = *(const short8*)&qkv[qoff];
    const short8 af1 = *(const short8*)&qkv[qoff + 32];

    for (int it = tid; it < 3136; it += 256) {
        const bool isK = it < 1568;
        const int task = isK ? it : it - 1568;
        const int key = task >> 3, oct = task & 7;
        const int pix = b * 4096 + (hby + key / 14) * 64 + hbx + key % 14;
        const uint4 d = *(const uint4*)&qkv[(size_t)pix * 768 + (isK ? 256 : 512) + hcol + oct * 8];
        if (isK) {
            uint32* dst = (uint32*)&KS[(oct >> 2) * 6272 + key * 32 + (oct & 3) * 8];
            dst[0] = d.x; dst[1] = d.y; dst[2] = d.z; dst[3] = d.w;
        } else {
            const ushort16* s8 = (const ushort16*)&d;
            #pragma unroll
            for (int j = 0; j < 8; ++j) VT[(oct * 8 + j) * 224 + key] = s8[j];
        }
    }
    for (int it = tid; it < 1792; it += 256)
        VT[(it / 28) * 224 + 196 + (it % 28)] = 0;
    __syncthreads();

    floatx4 acc[13];
    #pragma unroll
    for (int nt = 0; nt < 13; ++nt) {
        const int krow = (nt * 16 + l15) * 32 + kq8;
        const short8 bf0 = *(const short8*)&KS[krow];
        const short8 bf1 = *(const short8*)&KS[6272 + krow];
        floatx4 a = {0.0f, 0.0f, 0.0f, 0.0f};
        a = __builtin_amdgcn_mfma_f32_16x16x32_bf16(af0, bf0, a, 0, 0, 0);
        a = __builtin_amdgcn_mfma_f32_16x16x32_bf16(af1, bf1, a, 0, 0, 0);
        acc[nt] = a;
    }

    int kyA[13], kxA[13];
    #pragma unroll
    for (int nt = 0; nt < 13; ++nt) {
        const int kidx = nt * 16 + l15;
        kyA[nt] = hby + kidx / 14;
        kxA[nt] = hbx + kidx % 14;
    }

    const int crow = (lane >> 4) * 4;
    float rs[4];
    #pragma unroll
    for (int r = 0; r < 4; ++r) {
        const int pl = wid * 16 + crow + r;
        const int py = ty0 + (pl >> 3), px = tx0 + (pl & 7);
        const int sy = min(max(py - 3, 0), 57), sx = min(max(px - 3, 0), 57);
        float lv[13];
        float mx = -1e30f;
        #pragma unroll
        for (int nt = 0; nt < 13; ++nt) {
            const int kidx = nt * 16 + l15;
            const bool valid = (kidx < 196) &&
                               ((unsigned)(kyA[nt] - sy) < 7u) &&
                               ((unsigned)(kxA[nt] - sx) < 7u);
            lv[nt] = valid ? acc[nt][r] * 0.125f : -1e30f;
            mx = fmaxf(mx, lv[nt]);
        }
        #pragma unroll
        for (int off = 1; off < 16; off <<= 1) mx = fmaxf(mx, __shfl_xor(mx, off));
        float sme = 0.0f;
        #pragma unroll
        for (int nt = 0; nt < 13; ++nt) {
            const float e = exp2f((lv[nt] - mx) * 1.4426950408889634f);
            lv[nt] = e;
            sme += e;
        }
        #pragma unroll
        for (int off = 1; off < 16; off <<= 1) sme += __shfl_xor(sme, off);
        rs[r] = 1.0f / sme;
        #pragma unroll
        for (int nt = 0; nt < 13; ++nt)
            PL[pl * 208 + nt * 16 + l15] = f2us(lv[nt]);
    }
    __syncthreads();

    floatx4 oacc[4] = {};
    #pragma unroll
    for (int kc = 0; kc < 7; ++kc) {
        const short8 af = *(const short8*)&PL[(wid * 16 + l15) * 208 + kc * 32 + kq8];
        #pragma unroll
        for (int nd = 0; nd < 4; ++nd) {
            const short8 bf = *(const short8*)&VT[(nd * 16 + l15) * 224 + kc * 32 + kq8];
            oacc[nd] = __builtin_amdgcn_mfma_f32_16x16x32_bf16(af, bf, oacc[nd], 0, 0, 0);
        }
    }
    #pragma unroll
    for (int r = 0; r < 4; ++r) {
        const int pl = wid * 16 + crow + r;
        const int py = ty0 + (pl >> 3), px = tx0 + (pl & 7);
        const size_t o = (size_t)(b * 4096 + py * 64 + px) * 256 + hcol;
        #pragma unroll
        for (int nd = 0; nd < 4; ++nd)
            ao[o + nd * 16 + l15] = f2us(oacc[nd][r] * rs[r]);
    }
}

// ---------------------------------------------------------------------------
// FUSED tail: proj + residual + RMSNorm2 + ff1 + GEGLU + ff2 + residual.
// BM=16, grid 512 (~42 KB LDS -> 2 blocks/CU). x1 in registers.
// ---------------------------------------------------------------------------
__global__ __launch_bounds__(256) void fused_tail(const ushort16* __restrict__ A,
                                                  const ushort16* __restrict__ wprojT,
                                                  const ushort16* __restrict__ ff1wT,
                                                  const ushort16* __restrict__ ff2wT,
                                                  const float* __restrict__ bF,
                                                  const void* __restrict__ xres,
                                                  const void* __restrict__ n2w,
                                                  void* __restrict__ out,
                                                  const int* __restrict__ flag) {
    __shared__ ushort16 At[16 * 32];      // 1 KB
    __shared__ ushort16 Apad[16 * 264];   // 8.25 KB (y, then g)
    __shared__ ushort16 Bs[512 * 32];     // 32 KB
    __shared__ float red[4][16];

    const int f32 = flag[0];
    const int tid = threadIdx.x, lane = tid & 63, wid = tid >> 6;
    const int m0 = blockIdx.x * 16;
    const int nw = wid * 64;
    const int cr = lane >> 2, cc = (lane & 3) * 8;
    const int l15 = lane & 15, kq = (lane >> 4) * 8;
    const int crow = (lane >> 4) * 4;

    // ===== phase 1: proj GEMM (acc = ao @ wprojT) =====
    floatx4 acc[4] = {};
    for (int k0 = 0; k0 < 256; k0 += 32) {
        #pragma unroll
        for (int c = 0; c < 5; ++c) {
            const int ch = wid + c * 4;          // 0..16 used
            if (ch < 17) {
                const ushort16* g;
                ushort16* l;
                if (ch < 1) {
                    g = A + (size_t)(m0 + cr) * 256 + k0 + cc;
                    l = At;
                } else {
                    const int c2 = ch - 1;
                    g = wprojT + (size_t)(c2 * 16 + cr) * 256 + k0 + cc;
                    l = Bs + c2 * 512;
                }
                gl_lds16(g, l);
            }
        }
        __syncthreads();
        short8 af, bf[4];
        af = *(const short8*)&At[l15 * 32 + kq];
        #pragma unroll
        for (int nj = 0; nj < 4; ++nj)
            bf[nj] = *(const short8*)&Bs[(nw + nj * 16 + l15) * 32 + kq];
        #pragma unroll
        for (int nj = 0; nj < 4; ++nj)
            acc[nj] = __builtin_amdgcn_mfma_f32_16x16x32_bf16(af, bf[nj], acc[nj], 0, 0, 0);
        __syncthreads();
    }

    // ===== x1 = acc + bproj + x ; rmsnorm -> y in Apad =====
    float w2[4], bsv[4];
    #pragma unroll
    for (int nj = 0; nj < 4; ++nj) {
        const int n = nw + nj * 16 + l15;
        w2[nj] = ldflag(n2w, n, f32);
        bsv[nj] = bF[n];
    }
    float ps[4] = {};
    #pragma unroll
    for (int nj = 0; nj < 4; ++nj)
        #pragma unroll
        for (int r = 0; r < 4; ++r) {
            const int m = m0 + crow + r;
            const int n = nw + nj * 16 + l15;
            float v = acc[nj][r] + bsv[nj] + ldflag(xres, (size_t)m * 256 + n, f32);
            acc[nj][r] = v;            // x1 stays in regs
            ps[r] += v * v;
        }
    #pragma unroll
    for (int off = 1; off < 16; off <<= 1)
        #pragma unroll
        for (int r = 0; r < 4; ++r) ps[r] += __shfl_xor(ps[r], off);
    if (l15 == 0)
        #pragma unroll
        for (int r = 0; r < 4; ++r) red[wid][crow + r] = ps[r];
    __syncthreads();
    #pragma unroll
    for (int r = 0; r < 4; ++r) {
        const int row = crow + r;
        const float s = red[0][row] + red[1][row] + red[2][row] + red[3][row];
        const float rr = rsqrtf(s * (1.0f / 256.0f) + 1e-6f);
        #pragma unroll
        for (int nj = 0; nj < 4; ++nj) {
            const int n = nw + nj * 16 + l15;
            Apad[row * 264 + n] = f2us(acc[nj][r] * rr * w2[nj]);
        }
    }
    // (first ff1 k-step syncs before Apad reads)

    // ===== phase 2: ff1 (gate + value) =====
    floatx4 accg[4] = {}, accv[4] = {};
    for (int k0 = 0; k0 < 256; k0 += 32) {
        #pragma unroll
        for (int c = 0; c < 8; ++c) {
            const int ch = wid + c * 4;          // 0..31
            gl_lds16(ff1wT + (size_t)(ch * 16 + cr) * 256 + k0 + cc, Bs + ch * 512);
        }
        __syncthreads();
        short8 af, bg[4], bv[4];
        af = *(const short8*)&Apad[l15 * 264 + k0 + kq];
        #pragma unroll
        for (int nj = 0; nj < 4; ++nj) {
            bg[nj] = *(const short8*)&Bs[(nw + nj * 16 + l15) * 32 + kq];
            bv[nj] = *(const short8*)&Bs[(256 + nw + nj * 16 + l15) * 32 + kq];
        }
        #pragma unroll
        for (int nj = 0; nj < 4; ++nj) {
            accg[nj] = __builtin_amdgcn_mfma_f32_16x16x32_bf16(af, bg[nj], accg[nj], 0, 0, 0);
            accv[nj] = __builtin_amdgcn_mfma_f32_16x16x32_bf16(af, bv[nj], accv[nj], 0, 0, 0);
        }
        __syncthreads();
    }

    // ===== GEGLU -> g into Apad (y dead) =====
    #pragma unroll
    for (int nj = 0; nj < 4; ++nj) {
        const int n = nw + nj * 16 + l15;
        const float bg_ = bF[256 + n], bv_ = bF[512 + n];
        #pragma unroll
        for (int r = 0; r < 4; ++r) {
            const float gate = accg[nj][r] + bg_;
            const float val = accv[nj][r] + bv_;
            Apad[(crow + r) * 264 + n] = f2us(gelu_f(gate) * val);
        }
    }
    __syncthreads();

    // ===== phase 3: ff2 =====
    floatx4 acc2[4] = {};
    for (int k0 = 0; k0 < 256; k0 += 32) {
        #pragma unroll
        for (int c = 0; c < 4; ++c) {
            const int ch = wid + c * 4;          // 0..15
            gl_lds16(ff2wT + (size_t)(ch * 16 + cr) * 256 + k0 + cc, Bs + ch * 512);
        }
        __syncthreads();
        short8 af, bf[4];
        af = *(const short8*)&Apad[l15 * 264 + k0 + kq];
        #pragma unroll
        for (int nj = 0; nj < 4; ++nj)
            bf[nj] = *(const short8*)&Bs[(nw + nj * 16 + l15) * 32 + kq];
        #pragma unroll
        for (int nj = 0; nj < 4; ++nj)
            acc2[nj] = __builtin_amdgcn_mfma_f32_16x16x32_bf16(af, bf[nj], acc2[nj], 0, 0, 0);
        __syncthreads();
    }

    // ===== out = acc2 + ff2b + x1(regs) =====
    #pragma unroll
    for (int nj = 0; nj < 4; ++nj) {
        const int n = nw + nj * 16 + l15;
        const float bs = bF[768 + n];
        #pragma unroll
        for (int r = 0; r < 4; ++r) {
            const int m = m0 + crow + r;
            const size_t oi = (size_t)m * 256 + n;
            const float v = acc2[nj][r] + bs + acc[nj][r];
            if (f32) ((float*)out)[oi] = v;
            else     ((ushort16*)out)[oi] = f2us(v);
        }
    }
}

// ---------------------------------------------------------------------------
extern "C" void kernel_launch(void* const* d_in, const int* in_sizes, int n_in,
                              void* d_out, int out_size, void* d_ws, size_t ws_size,
                              hipStream_t stream) {
    const void* x   = d_in[0];
    const void* n1w = d_in[1];
    const void* n2w = d_in[2];
    WSrc ws_src{d_in[3], d_in[4], d_in[6], d_in[8], d_in[5], d_in[7], d_in[9]};

    char* ws = (char*)d_ws;
    int*      flag = (int*)ws;
    ushort16* wT   = (ushort16*)(ws + 4096);              // ends 921600
    float*    bF   = (float*)(ws + 921600);               // 4 KB
    float2*   lut  = (float2*)(ws + 925696);              // 32 KB
    ushort16* qkv  = (ushort16*)(ws + (5 << 20));
    ushort16* ao   = (ushort16*)(ws + (size_t)(17 << 20));

    ushort16* wqkvT  = wT;
    ushort16* wprojT = wT + 196608;
    ushort16* ff1wT  = wT + 262144;
    ushort16* ff2wT  = wT + 393216;

    detect_kernel<<<1, 64, 0, stream>>>((const ushort16*)x, flag);
    cvt_kernel<<<114, 256, 0, stream>>>(ws_src, wT, bF, lut, flag);
    // qkv = rope2d(rmsnorm(x, n1w)) @ w_qkv
    fused_qkv<<<dim3(3, 512), 256, 0, stream>>>(x, n1w, wqkvT, lut, qkv, flag);
    // ao = neighborhood_attn(qkv)
    attn_kernel<<<512, 256, 0, stream>>>(qkv, ao);
    // out = x1 + geglu(rmsnorm(x1) @ ff1 + b) @ ff2 + b,  x1 = x + ao@wproj + bproj
    fused_tail<<<512, 256, 0, stream>>>(ao, wprojT, ff1wT, ff2wT, bF, x, n2w, d_out, flag);
}

// Round 12
// 147.279 us; speedup vs baseline: 1.0423x; 1.0423x over previous
//
#include <hip/hip_runtime.h>
#include <hip/hip_bf16.h>

// ---------------------------------------------------------------------------
// NeighborhoodAttentionBlock: B=2, H=W=64, C=256, nh=4, hd=64, k=7
// R12 = R9 verbatim (verified best, 148 µs): attn in R5-verified layout;
// proj+rms2+ff1+geglu+ff2 merged into one row-local kernel (x1 in regs,
// y/g in LDS). 5 dispatches.
// ---------------------------------------------------------------------------

#define ROWS 8192
typedef unsigned int uint32;
typedef unsigned short ushort16;
typedef __attribute__((ext_vector_type(8))) short short8;
typedef __attribute__((ext_vector_type(4))) float floatx4;

__device__ __forceinline__ float bf2f(__hip_bfloat16 b) { return __bfloat162float(b); }
__device__ __forceinline__ float us2f(ushort16 u) {
    return __uint_as_float(((uint32)u) << 16);
}
__device__ __forceinline__ ushort16 f2us(float f) {
    __hip_bfloat16 h = __float2bfloat16(f);
    return *(ushort16*)&h;
}
__device__ __forceinline__ float ldflag(const void* p, size_t i, int f32) {
    return f32 ? ((const float*)p)[i] : bf2f(((const __hip_bfloat16*)p)[i]);
}

__device__ __forceinline__ void gl_lds16(const void* gptr, void* lptr) {
    __builtin_amdgcn_global_load_lds(
        (const __attribute__((address_space(1))) uint32*)gptr,
        (__attribute__((address_space(3))) uint32*)lptr, 16, 0, 0);
}

// Fast exact-erf gelu: Abramowitz-Stegun 7.1.26 (max err 1.5e-7) + __expf.
__device__ __forceinline__ float gelu_f(float gate) {
    const float z = gate * 0.70710678118654752f;
    const float az = fabsf(z);
    const float t1 = 1.0f / fmaf(0.3275911f, az, 1.0f);
    const float poly = ((((1.061405429f * t1 - 1.453152027f) * t1 + 1.421413741f) * t1
                         - 0.284496736f) * t1 + 0.254829592f) * t1;
    float erfv = 1.0f - poly * __expf(-az * az);
    erfv = (z < 0.0f) ? -erfv : erfv;
    return 0.5f * gate * (1.0f + erfv);
}

// ---------------------------------------------------------------------------
// Dtype detector (verified).
// ---------------------------------------------------------------------------
__global__ __launch_bounds__(64) void detect_kernel(const ushort16* __restrict__ xu,
                                                    int* __restrict__ flag) {
    const int lane = threadIdx.x;
    const float v = us2f(xu[lane * 62]);
    const float a = fabsf(v);
    const bool sane = (a < 1e4f) && (a > 1e-8f);
    const unsigned long long m = __ballot(sane);
    if (lane == 0) flag[0] = (__popcll(m) < 32) ? 1 : 0;
}

// ---------------------------------------------------------------------------
// Weight convert + transpose (verified) + bias block + rope LUT block.
// ---------------------------------------------------------------------------
struct WSrc {
    const void *wqkv, *wproj, *ff1w, *ff2w, *bproj, *ff1b, *ff2b;
};
__global__ __launch_bounds__(256) void cvt_kernel(WSrc s, ushort16* __restrict__ wT,
                                                  float* __restrict__ bF,
                                                  float2* __restrict__ lut,
                                                  const int* __restrict__ flag) {
    const int f32 = flag[0];
    const int bid = blockIdx.x, tid = threadIdx.x;
    if (bid == 112) {
        #pragma unroll
        for (int it = 0; it < 4; ++it) {
            const int j = it * 256 + tid;
            float v;
            if (j < 256)      v = ldflag(s.bproj, j, f32);
            else if (j < 768) v = ldflag(s.ff1b, j - 256, f32);
            else              v = ldflag(s.ff2b, j - 768, f32);
            bF[j] = v;
        }
        return;
    }
    if (bid == 113) {
        #pragma unroll
        for (int it = 0; it < 16; ++it) {
            const int idx = it * 256 + tid;       // 0..4095
            const int pos = idx >> 6, j = idx & 63;
            const float inv = expf(-(float)j * (9.210340371976184f / 64.0f));
            const float th = (float)pos * inv;
            lut[idx] = make_float2(cosf(th), sinf(th));
        }
        return;
    }
    const void* src; int N, kt, nt, base;
    if (bid < 48)      { src = s.wqkv;  N = 768; kt = bid / 12;      nt = bid % 12;      base = 0; }
    else if (bid < 64) { const int l = bid - 48; src = s.wproj; N = 256; kt = l / 4; nt = l % 4; base = 196608; }
    else if (bid < 96) { const int l = bid - 64; src = s.ff1w;  N = 512; kt = l / 8; nt = l % 8; base = 262144; }
    else               { const int l = bid - 96; src = s.ff2w;  N = 256; kt = l / 4; nt = l % 4; base = 393216; }

    __shared__ ushort16 T[64][65];
    const int r0 = tid >> 6, c = tid & 63;
    #pragma unroll
    for (int j = 0; j < 16; ++j) {
        const int r = j * 4 + r0;
        T[r][c] = f2us(ldflag(src, (size_t)(kt * 64 + r) * N + nt * 64 + c, f32));
    }
    __syncthreads();
    const int n = tid >> 2, kg = tid & 3;
    #pragma unroll
    for (int j = 0; j < 16; ++j) {
        const int k = kg * 16 + j;
        wT[base + (size_t)(nt * 64 + n) * 256 + kt * 64 + k] = T[k][n];
    }
}

// ---------------------------------------------------------------------------
// FUSED rmsnorm1 + rope2d + qkv GEMM (rope via LUT). (verified R8/R9)
// ---------------------------------------------------------------------------
__global__ __launch_bounds__(256) void fused_qkv(const void* __restrict__ x,
                                                 const void* __restrict__ n1w,
                                                 const ushort16* __restrict__ wqkvT,
                                                 const float2* __restrict__ lut,
                                                 ushort16* __restrict__ qkv,
                                                 const int* __restrict__ flag) {
    __shared__ ushort16 Apad[32 * 264];
    __shared__ ushort16 Bs[256 * 32];

    const int f32 = flag[0];
    const int tid = threadIdx.x, lane = tid & 63, wid = tid >> 6;
    const int l15 = lane & 15, kq8 = (lane >> 4) * 8;
    const int n0 = blockIdx.x * 256, m0 = blockIdx.y * 32;
    const int nw = wid * 64;
    const int cr = lane >> 2, cc = (lane & 3) * 8;

    {
        const int row = tid >> 3, s = tid & 7;
        const int gm = m0 + row;
        float v[32];
        #pragma unroll
        for (int j = 0; j < 8; ++j) {
            const size_t off = (size_t)gm * 256 + s * 32 + j * 4;
            if (f32) {
                const float4 d = *(const float4*)((const float*)x + off);
                v[j * 4] = d.x; v[j * 4 + 1] = d.y; v[j * 4 + 2] = d.z; v[j * 4 + 3] = d.w;
            } else {
                const ushort4 d = *(const ushort4*)((const ushort16*)x + off);
                v[j * 4] = us2f(d.x); v[j * 4 + 1] = us2f(d.y);
                v[j * 4 + 2] = us2f(d.z); v[j * 4 + 3] = us2f(d.w);
            }
        }
        float sq = 0.0f;
        #pragma unroll
        for (int i = 0; i < 32; ++i) sq += v[i] * v[i];
        sq += __shfl_xor(sq, 1);
        sq += __shfl_xor(sq, 2);
        sq += __shfl_xor(sq, 4);
        const float rr = rsqrtf(sq * (1.0f / 256.0f) + 1e-6f);

        const int py = (gm >> 6) & 63, px = gm & 63;
        #pragma unroll
        for (int j = 0; j < 8; ++j) {
            const int c0 = s * 32 + j * 4;
            float nv[4];
            #pragma unroll
            for (int u = 0; u < 4; ++u)
                nv[u] = v[j * 4 + u] * rr * ldflag(n1w, c0 + u, f32);
            const int pos = (c0 < 128) ? py : px;
            const int j0 = (c0 & 127) >> 1;
            #pragma unroll
            for (int p = 0; p < 2; ++p) {
                const float2 cs = lut[pos * 64 + j0 + p];
                const float a = nv[p * 2], b = nv[p * 2 + 1];
                nv[p * 2]     = a * cs.x - b * cs.y;
                nv[p * 2 + 1] = a * cs.y + b * cs.x;
            }
            ushort4 o;
            o.x = f2us(nv[0]); o.y = f2us(nv[1]); o.z = f2us(nv[2]); o.w = f2us(nv[3]);
            *(ushort4*)&Apad[row * 264 + c0] = o;
        }
    }
    __syncthreads();

    floatx4 acc[2][4] = {};
    for (int k0 = 0; k0 < 256; k0 += 32) {
        #pragma unroll
        for (int c = 0; c < 4; ++c) {
            const int ch = wid + c * 4;
            gl_lds16(wqkvT + (size_t)(n0 + ch * 16 + cr) * 256 + k0 + cc, Bs + ch * 512);
        }
        __syncthreads();
        short8 af[2], bf[4];
        #pragma unroll
        for (int mi = 0; mi < 2; ++mi)
            af[mi] = *(const short8*)&Apad[(mi * 16 + l15) * 264 + k0 + kq8];
        #pragma unroll
        for (int nj = 0; nj < 4; ++nj)
            bf[nj] = *(const short8*)&Bs[(nw + nj * 16 + l15) * 32 + kq8];
        #pragma unroll
        for (int mi = 0; mi < 2; ++mi)
            #pragma unroll
            for (int nj = 0; nj < 4; ++nj)
                acc[mi][nj] = __builtin_amdgcn_mfma_f32_16x16x32_bf16(af[mi], bf[nj], acc[mi][nj], 0, 0, 0);
        __syncthreads();
    }

    const int crow = (lane >> 4) * 4;
    #pragma unroll
    for (int mi = 0; mi < 2; ++mi)
        #pragma unroll
        for (int nj = 0; nj < 4; ++nj)
            #pragma unroll
            for (int r = 0; r < 4; ++r) {
                const int m = m0 + mi * 16 + crow + r;
                const int n = n0 + nw + nj * 16 + l15;
                qkv[(size_t)m * 768 + n] = f2us(acc[mi][nj][r]);
            }
}

// ---------------------------------------------------------------------------
// Neighborhood attention (R5-verified version).
// ---------------------------------------------------------------------------
__global__ __launch_bounds__(256) void attn_kernel(const ushort16* __restrict__ qkv,
                                                   ushort16* __restrict__ ao) {
    __shared__ ushort16 smem[40208];
    ushort16* const KS = smem;
    ushort16* const VT = smem + 12544;
    ushort16* const PL = smem + 26880;

    const int tid = threadIdx.x, lane = tid & 63, wid = tid >> 6;
    const int l15 = lane & 15, kq8 = (lane >> 4) * 8;
    const int bid = blockIdx.x;
    const int h = bid & 3;
    const int t = (bid >> 2) & 63;
    const int b = bid >> 8;
    const int ty0 = (t >> 3) * 8, tx0 = (t & 7) * 8;
    const int hby = min(max(ty0 - 3, 0), 50);
    const int hbx = min(max(tx0 - 3, 0), 50);
    const int hcol = h * 64;

    const int qpl = wid * 16 + l15;
    const int qpy = ty0 + (qpl >> 3), qpx = tx0 + (qpl & 7);
    const size_t qoff = (size_t)(b * 4096 + qpy * 64 + qpx) * 768 + hcol + kq8;
    const short8 af0 = *(const short8*)&qkv[qoff];
    const short8 af1 = *(const short8*)&qkv[qoff + 32];

    for (int it = tid; it < 3136; it += 256) {
        const bool isK = it < 1568;
        const int task = isK ? it : it - 1568;
        const int key = task >> 3, oct = task & 7;
        const int pix = b * 4096 + (hby + key / 14) * 64 + hbx + key % 14;
        const uint4 d = *(const uint4*)&qkv[(size_t)pix * 768 + (isK ? 256 : 512) + hcol + oct * 8];
        if (isK) {
            uint32* dst = (uint32*)&KS[(oct >> 2) * 6272 + key * 32 + (oct & 3) * 8];
            dst[0] = d.x; dst[1] = d.y; dst[2] = d.z; dst[3] = d.w;
        } else {
            const ushort16* s8 = (const ushort16*)&d;
            #pragma unroll
            for (int j = 0; j < 8; ++j) VT[(oct * 8 + j) * 224 + key] = s8[j];
        }
    }
    for (int it = tid; it < 1792; it += 256)
        VT[(it / 28) * 224 + 196 + (it % 28)] = 0;
    __syncthreads();

    floatx4 acc[13];
    #pragma unroll
    for (int nt = 0; nt < 13; ++nt) {
        const int krow = (nt * 16 + l15) * 32 + kq8;
        const short8 bf0 = *(const short8*)&KS[krow];
        const short8 bf1 = *(const short8*)&KS[6272 + krow];
        floatx4 a = {0.0f, 0.0f, 0.0f, 0.0f};
        a = __builtin_amdgcn_mfma_f32_16x16x32_bf16(af0, bf0, a, 0, 0, 0);
        a = __builtin_amdgcn_mfma_f32_16x16x32_bf16(af1, bf1, a, 0, 0, 0);
        acc[nt] = a;
    }

    int kyA[13], kxA[13];
    #pragma unroll
    for (int nt = 0; nt < 13; ++nt) {
        const int kidx = nt * 16 + l15;
        kyA[nt] = hby + kidx / 14;
        kxA[nt] = hbx + kidx % 14;
    }

    const int crow = (lane >> 4) * 4;
    float rs[4];
    #pragma unroll
    for (int r = 0; r < 4; ++r) {
        const int pl = wid * 16 + crow + r;
        const int py = ty0 + (pl >> 3), px = tx0 + (pl & 7);
        const int sy = min(max(py - 3, 0), 57), sx = min(max(px - 3, 0), 57);
        float lv[13];
        float mx = -1e30f;
        #pragma unroll
        for (int nt = 0; nt < 13; ++nt) {
            const int kidx = nt * 16 + l15;
            const bool valid = (kidx < 196) &&
                               ((unsigned)(kyA[nt] - sy) < 7u) &&
                               ((unsigned)(kxA[nt] - sx) < 7u);
            lv[nt] = valid ? acc[nt][r] * 0.125f : -1e30f;
            mx = fmaxf(mx, lv[nt]);
        }
        #pragma unroll
        for (int off = 1; off < 16; off <<= 1) mx = fmaxf(mx, __shfl_xor(mx, off));
        float sme = 0.0f;
        #pragma unroll
        for (int nt = 0; nt < 13; ++nt) {
            const float e = exp2f((lv[nt] - mx) * 1.4426950408889634f);
            lv[nt] = e;
            sme += e;
        }
        #pragma unroll
        for (int off = 1; off < 16; off <<= 1) sme += __shfl_xor(sme, off);
        rs[r] = 1.0f / sme;
        #pragma unroll
        for (int nt = 0; nt < 13; ++nt)
            PL[pl * 208 + nt * 16 + l15] = f2us(lv[nt]);
    }
    __syncthreads();

    floatx4 oacc[4] = {};
    #pragma unroll
    for (int kc = 0; kc < 7; ++kc) {
        const short8 af = *(const short8*)&PL[(wid * 16 + l15) * 208 + kc * 32 + kq8];
        #pragma unroll
        for (int nd = 0; nd < 4; ++nd) {
            const short8 bf = *(const short8*)&VT[(nd * 16 + l15) * 224 + kc * 32 + kq8];
            oacc[nd] = __builtin_amdgcn_mfma_f32_16x16x32_bf16(af, bf, oacc[nd], 0, 0, 0);
        }
    }
    #pragma unroll
    for (int r = 0; r < 4; ++r) {
        const int pl = wid * 16 + crow + r;
        const int py = ty0 + (pl >> 3), px = tx0 + (pl & 7);
        const size_t o = (size_t)(b * 4096 + py * 64 + px) * 256 + hcol;
        #pragma unroll
        for (int nd = 0; nd < 4; ++nd)
            ao[o + nd * 16 + l15] = f2us(oacc[nd][r] * rs[r]);
    }
}

// ---------------------------------------------------------------------------
// FUSED tail: proj GEMM + residual + RMSNorm2 + ff1 + GEGLU + ff2 + residual.
// Block = 32 rows (m0 = blockIdx.x*32), 256 blocks. x1 lives in registers
// (proj acc layout == ff2 epilogue layout); y and g live in LDS Apad.
// ---------------------------------------------------------------------------
__global__ __launch_bounds__(256) void fused_tail(const ushort16* __restrict__ A,
                                                  const ushort16* __restrict__ wprojT,
                                                  const ushort16* __restrict__ ff1wT,
                                                  const ushort16* __restrict__ ff2wT,
                                                  const float* __restrict__ bF,
                                                  const void* __restrict__ xres,
                                                  const void* __restrict__ n2w,
                                                  void* __restrict__ out,
                                                  const int* __restrict__ flag) {
    __shared__ ushort16 At[32 * 32];      // 2 KB
    __shared__ ushort16 Apad[32 * 264];   // 16.5 KB (y, then g)
    __shared__ ushort16 Bs[512 * 32];     // 32 KB
    __shared__ float red[4][32];

    const int f32 = flag[0];
    const int tid = threadIdx.x, lane = tid & 63, wid = tid >> 6;
    const int m0 = blockIdx.x * 32;
    const int nw = wid * 64;
    const int cr = lane >> 2, cc = (lane & 3) * 8;
    const int l15 = lane & 15, kq = (lane >> 4) * 8;
    const int crow = (lane >> 4) * 4;

    // ===== phase 1: proj GEMM (acc = ao @ wprojT) =====
    floatx4 acc[2][4] = {};
    for (int k0 = 0; k0 < 256; k0 += 32) {
        #pragma unroll
        for (int c = 0; c < 5; ++c) {
            const int ch = wid + c * 4;          // wave-uniform
            if (ch < 18) {
                const ushort16* g;
                ushort16* l;
                if (ch < 2) {
                    g = A + (size_t)(m0 + ch * 16 + cr) * 256 + k0 + cc;
                    l = At + ch * 512;
                } else {
                    const int c2 = ch - 2;
                    g = wprojT + (size_t)(c2 * 16 + cr) * 256 + k0 + cc;
                    l = Bs + c2 * 512;
                }
                gl_lds16(g, l);
            }
        }
        __syncthreads();
        short8 af[2], bf[4];
        #pragma unroll
        for (int mi = 0; mi < 2; ++mi)
            af[mi] = *(const short8*)&At[(mi * 16 + l15) * 32 + kq];
        #pragma unroll
        for (int nj = 0; nj < 4; ++nj)
            bf[nj] = *(const short8*)&Bs[(nw + nj * 16 + l15) * 32 + kq];
        #pragma unroll
        for (int mi = 0; mi < 2; ++mi)
            #pragma unroll
            for (int nj = 0; nj < 4; ++nj)
                acc[mi][nj] = __builtin_amdgcn_mfma_f32_16x16x32_bf16(af[mi], bf[nj], acc[mi][nj], 0, 0, 0);
        __syncthreads();
    }

    // ===== x1 = acc + bproj + x ; rmsnorm -> y in Apad =====
    float w2[4], bsv[4];
    #pragma unroll
    for (int nj = 0; nj < 4; ++nj) {
        const int n = nw + nj * 16 + l15;
        w2[nj] = ldflag(n2w, n, f32);
        bsv[nj] = bF[n];
    }
    float ps[2][4] = {};
    #pragma unroll
    for (int mi = 0; mi < 2; ++mi)
        #pragma unroll
        for (int nj = 0; nj < 4; ++nj)
            #pragma unroll
            for (int r = 0; r < 4; ++r) {
                const int m = m0 + mi * 16 + crow + r;
                const int n = nw + nj * 16 + l15;
                float v = acc[mi][nj][r] + bsv[nj] + ldflag(xres, (size_t)m * 256 + n, f32);
                acc[mi][nj][r] = v;            // x1 stays in regs
                ps[mi][r] += v * v;
            }
    #pragma unroll
    for (int off = 1; off < 16; off <<= 1)
        #pragma unroll
        for (int mi = 0; mi < 2; ++mi)
            #pragma unroll
            for (int r = 0; r < 4; ++r) ps[mi][r] += __shfl_xor(ps[mi][r], off);
    if (l15 == 0)
        #pragma unroll
        for (int mi = 0; mi < 2; ++mi)
            #pragma unroll
            for (int r = 0; r < 4; ++r) red[wid][mi * 16 + crow + r] = ps[mi][r];
    __syncthreads();
    #pragma unroll
    for (int mi = 0; mi < 2; ++mi)
        #pragma unroll
        for (int r = 0; r < 4; ++r) {
            const int row = mi * 16 + crow + r;
            const float s = red[0][row] + red[1][row] + red[2][row] + red[3][row];
            const float rr = rsqrtf(s * (1.0f / 256.0f) + 1e-6f);
            #pragma unroll
            for (int nj = 0; nj < 4; ++nj) {
                const int n = nw + nj * 16 + l15;
                Apad[row * 264 + n] = f2us(acc[mi][nj][r] * rr * w2[nj]);
            }
        }
    // (no barrier needed here: first ff1 k-step has a sync before Apad reads)

    // ===== phase 2: ff1 (gate + value) =====
    floatx4 accg[2][4] = {}, accv[2][4] = {};
    for (int k0 = 0; k0 < 256; k0 += 32) {
        #pragma unroll
        for (int c = 0; c < 8; ++c) {
            const int ch = wid + c * 4;          // 0..31
            gl_lds16(ff1wT + (size_t)(ch * 16 + cr) * 256 + k0 + cc, Bs + ch * 512);
        }
        __syncthreads();
        short8 af[2], bg[4], bv[4];
        #pragma unroll
        for (int mi = 0; mi < 2; ++mi)
            af[mi] = *(const short8*)&Apad[(mi * 16 + l15) * 264 + k0 + kq];
        #pragma unroll
        for (int nj = 0; nj < 4; ++nj) {
            bg[nj] = *(const short8*)&Bs[(nw + nj * 16 + l15) * 32 + kq];
            bv[nj] = *(const short8*)&Bs[(256 + nw + nj * 16 + l15) * 32 + kq];
        }
        #pragma unroll
        for (int mi = 0; mi < 2; ++mi)
            #pragma unroll
            for (int nj = 0; nj < 4; ++nj) {
                accg[mi][nj] = __builtin_amdgcn_mfma_f32_16x16x32_bf16(af[mi], bg[nj], accg[mi][nj], 0, 0, 0);
                accv[mi][nj] = __builtin_amdgcn_mfma_f32_16x16x32_bf16(af[mi], bv[nj], accv[mi][nj], 0, 0, 0);
            }
        __syncthreads();
    }

    // ===== GEGLU -> g into Apad (y dead) =====
    #pragma unroll
    for (int mi = 0; mi < 2; ++mi)
        #pragma unroll
        for (int nj = 0; nj < 4; ++nj) {
            const int n = nw + nj * 16 + l15;
            const float bg_ = bF[256 + n], bv_ = bF[512 + n];
            #pragma unroll
            for (int r = 0; r < 4; ++r) {
                const float gate = accg[mi][nj][r] + bg_;
                const float val = accv[mi][nj][r] + bv_;
                Apad[(mi * 16 + crow + r) * 264 + n] = f2us(gelu_f(gate) * val);
            }
        }
    __syncthreads();

    // ===== phase 3: ff2 =====
    floatx4 acc2[2][4] = {};
    for (int k0 = 0; k0 < 256; k0 += 32) {
        #pragma unroll
        for (int c = 0; c < 4; ++c) {
            const int ch = wid + c * 4;          // 0..15
            gl_lds16(ff2wT + (size_t)(ch * 16 + cr) * 256 + k0 + cc, Bs + ch * 512);
        }
        __syncthreads();
        short8 af[2], bf[4];
        #pragma unroll
        for (int mi = 0; mi < 2; ++mi)
            af[mi] = *(const short8*)&Apad[(mi * 16 + l15) * 264 + k0 + kq];
        #pragma unroll
        for (int nj = 0; nj < 4; ++nj)
            bf[nj] = *(const short8*)&Bs[(nw + nj * 16 + l15) * 32 + kq];
        #pragma unroll
        for (int mi = 0; mi < 2; ++mi)
            #pragma unroll
            for (int nj = 0; nj < 4; ++nj)
                acc2[mi][nj] = __builtin_amdgcn_mfma_f32_16x16x32_bf16(af[mi], bf[nj], acc2[mi][nj], 0, 0, 0);
        __syncthreads();
    }

    // ===== out = acc2 + ff2b + x1(regs) =====
    #pragma unroll
    for (int mi = 0; mi < 2; ++mi)
        #pragma unroll
        for (int nj = 0; nj < 4; ++nj) {
            const int n = nw + nj * 16 + l15;
            const float bs = bF[768 + n];
            #pragma unroll
            for (int r = 0; r < 4; ++r) {
                const int m = m0 + mi * 16 + crow + r;
                const size_t oi = (size_t)m * 256 + n;
                const float v = acc2[mi][nj][r] + bs + acc[mi][nj][r];
                if (f32) ((float*)out)[oi] = v;
                else     ((ushort16*)out)[oi] = f2us(v);
            }
        }
}

// ---------------------------------------------------------------------------
extern "C" void kernel_launch(void* const* d_in, const int* in_sizes, int n_in,
                              void* d_out, int out_size, void* d_ws, size_t ws_size,
                              hipStream_t stream) {
    const void* x   = d_in[0];
    const void* n1w = d_in[1];
    const void* n2w = d_in[2];
    WSrc ws_src{d_in[3], d_in[4], d_in[6], d_in[8], d_in[5], d_in[7], d_in[9]};

    char* ws = (char*)d_ws;
    int*      flag = (int*)ws;
    ushort16* wT   = (ushort16*)(ws + 4096);              // ends 921600
    float*    bF   = (float*)(ws + 921600);               // 4 KB
    float2*   lut  = (float2*)(ws + 925696);              // 32 KB
    ushort16* qkv  = (ushort16*)(ws + (5 << 20));
    ushort16* ao   = (ushort16*)(ws + (size_t)(17 << 20));

    ushort16* wqkvT  = wT;
    ushort16* wprojT = wT + 196608;
    ushort16* ff1wT  = wT + 262144;
    ushort16* ff2wT  = wT + 393216;

    detect_kernel<<<1, 64, 0, stream>>>((const ushort16*)x, flag);
    cvt_kernel<<<114, 256, 0, stream>>>(ws_src, wT, bF, lut, flag);
    // qkv = rope2d(rmsnorm(x, n1w)) @ w_qkv
    fused_qkv<<<dim3(3, 256), 256, 0, stream>>>(x, n1w, wqkvT, lut, qkv, flag);
    // ao = neighborhood_attn(qkv)
    attn_kernel<<<512, 256, 0, stream>>>(qkv, ao);
    // out = x1 + geglu(rmsnorm(x1) @ ff1 + b) @ ff2 + b,  x1 = x + ao@wproj + bproj
    fused_tail<<<256, 256, 0, stream>>>(ao, wprojT, ff1wT, ff2wT, bF, x, n2w, d_out, flag);
}